// Round 10
// baseline (17735.320 us; speedup 1.0000x reference)
//
#include <hip/hip_runtime.h>

// ---- problem dims ----
#define Bn   256
#define Tn   512
#define Fn   5
#define Hn   512
#define BBn  128
#define KSn  544          // 512 (H) + 5 (x) + pad to 17*32
#define KSP  552          // LDS row stride (shorts) for 544-col tiles: +8 -> 2-way banks only
#define BBP  136          // LDS row stride (shorts) for 128-col tiles
#define NC   8            // clusters (XCD round-robin by blockIdx%8 — probed, not assumed)
#define WPC  32           // workgroups per cluster
#define NWG  (NC*WPC)

typedef __attribute__((ext_vector_type(8))) short bf16x8;
typedef __attribute__((ext_vector_type(4))) float f32x4;
typedef unsigned long long u64;

// ---- d_ws layout (bytes) ----
#define WS_BAR   0                        // per-cluster slow-path counters, 128B apart
#define WS_PRB   1024                     // (legacy, unused)
#define WS_DC    2048                     // device-wide startup barrier counter
#define WS_XCC   4096                     // per-WG XCC id table (256 ints)
#define WS_POK   5120                     // per-WG probe verdicts
#define WS_PDT   6144                     // per-WG probe data slots (256 x 64B)
#define WS_H     24576                    // h_shared [Bn][KSn] bf16 (cols 512..516 = x_t, rest 0)
#define WS_HL    (WS_H   + Bn*KSn*2)      // hlstm    [Bn][KSn] bf16
#define WS_FEAT  (WS_HL  + Bn*KSn*2)      // 64KB region, reused for flag-barrier arrays:
#define WS_ARR   WS_FEAT                  //   arrival slots [8 clusters][32 WGs x 64B]
#define WS_BFL   (WS_FEAT + 16384)        //   broadcast flags [8 clusters][128B]
#define WS_WH    (WS_FEAT + Bn*BBn*2)     // Wh_ext   [2048][KSn] bf16 (k>=512 -> Wi, pad 0)
#define WS_BB    (WS_WH  + 2048*KSn*2)    // bb_ext   [128][KSn] bf16
#define WS_FF    (WS_BB  + 128*KSn*2)     // ff       [4][Hn][BBn] bf16

// ---- dynamic LDS layout (bytes) ----
#define LB_A     0                        // activation stage: 32*KSP*2 = 35328 (h / hlstm)
#define LB_WH    (LB_A + 32*KSP*2)        // Wh slice: [4 gates][16 cols][KSP] = 70656
#define LB_FF    (LB_WH + 64*KSP*2)       // ff slice: [4 mats][16 cols][BBP] = 17408
#define LB_FT    (LB_FF + 64*BBP*2)       // feat tile [32][BBP] bf16 = 8704
#define DYN_LDS  (LB_FT + 32*BBP*2)       // = 132096 (+9216 static lbuf = 141312 <= 160K)

// ---- d_out layout (floats) ----
#define YO 0
#define EO (Bn*Tn*2)
#define HO (EO + Bn*Tn)
#define CO (HO + Bn*Hn)

__device__ __forceinline__ unsigned short f2bf(float f) {
  union { float f; unsigned u; } v; v.f = f;
  unsigned r = v.u + 0x7FFFu + ((v.u >> 16) & 1u);
  return (unsigned short)(r >> 16);
}
__device__ __forceinline__ float bf2f(unsigned short u) {
  union { unsigned u; float f; } v; v.u = ((unsigned)u) << 16;
  return v.f;
}
__device__ __forceinline__ float sigm(float x) { return 1.f / (1.f + __expf(-x)); }
__device__ __forceinline__ float tanhx(float x) {
  float e = __expf(2.f * x);
  return 1.f - 2.f / (e + 1.f);
}

// PROVEN coherence primitives (rounds 7-8): relaxed agent-scope atomics lower to plain
// sc1 (L1-bypassing, L2-served, coalescable) loads/stores. Round-9's asm dwordx4-sc1
// experiment produced stale data -> reverted; only these primitives cross WG boundaries.
__device__ __forceinline__ u64 ldq_agent(const void* p) {
  return __hip_atomic_load((const u64*)p, __ATOMIC_RELAXED, __HIP_MEMORY_SCOPE_AGENT);
}
__device__ __forceinline__ int ldi_agent(const void* p) {
  return __hip_atomic_load((const int*)p, __ATOMIC_RELAXED, __HIP_MEMORY_SCOPE_AGENT);
}
__device__ __forceinline__ void sti_agent(int* p, int v) {
  __hip_atomic_store(p, v, __ATOMIC_RELAXED, __HIP_MEMORY_SCOPE_AGENT);
}

// Stage a 32-row x 544-col bf16 tile from global into LDS (row stride KSP*2).
// 17 independent 8B agent loads -> statically-indexed regs (all in flight), then the
// LDS writes (incremental vmcnt waits). Proven round 8.
__device__ __forceinline__ void stage32(const char* src, char* dst, int tid) {
  u64 rg[17];
  #pragma unroll
  for (int i = 0; i < 17; ++i) rg[i] = ldq_agent(src + (tid + i * 256) * 8);
  #pragma unroll
  for (int i = 0; i < 17; ++i) {
    int idx = tid + i * 256;
    int r = idx / 136, ch = idx - r * 136;
    *(u64*)(dst + r * (KSP * 2) + ch * 8) = rg[i];
  }
}

// ---------------- weight prep ----------------
__global__ void __launch_bounds__(256) prep_weights(
    const float* __restrict__ Wh, const float* __restrict__ Wi, const float* __restrict__ bbW,
    const float* __restrict__ f1W, const float* __restrict__ f2W,
    const float* __restrict__ taW, const float* __restrict__ tbW, char* __restrict__ ws)
{
  unsigned short* wh = (unsigned short*)(ws + WS_WH);
  unsigned short* bb = (unsigned short*)(ws + WS_BB);
  unsigned short* ff = (unsigned short*)(ws + WS_FF);
  const int n1 = 2048 * KSn, n2 = 128 * KSn, n3 = Hn * BBn;
  const int ntot = n1 + n2 + 4 * n3;
  for (int i = blockIdx.x * blockDim.x + threadIdx.x; i < ntot; i += gridDim.x * blockDim.x) {
    if (i < n1) {
      int c = i / KSn, k = i % KSn;
      float v = (k < 512) ? Wh[c * 512 + k] : ((k < 517) ? Wi[c * 5 + (k - 512)] : 0.f);
      wh[i] = f2bf(v);
    } else if (i < n1 + n2) {
      int j = i - n1; int o = j / KSn, k = j % KSn;
      float v = (k < 512) ? bbW[o * 517 + 5 + k] : ((k < 517) ? bbW[o * 517 + (k - 512)] : 0.f);
      bb[j] = f2bf(v);
    } else {
      int j = i - n1 - n2; int m = j / n3; int r = j % n3;
      const float* src = (m == 0) ? f1W : (m == 1) ? f2W : (m == 2) ? taW : tbW;
      ff[j] = f2bf(src[r]);
    }
  }
}

// ---------------- barriers ----------------
// FLAG barrier (fast path): arrival = one agent STORE per WG to its own 64B slot (no
// RMW serialization — round-8's 5us/barrier was 32 CUs RMW-spinning one L2 address).
// Leader (wg 0) polls all 32 slots with batched agent loads, then agent-stores the
// epoch to a broadcast flag; followers poll only that flag. Visibility relies solely on
// round-7/8-proven facts: stores are L2-committed at __syncthreads; agent loads read L2.
__device__ __forceinline__ void flag_bar(int* arr, int* bfl, int wg, int e) {
  __syncthreads();
  if (threadIdx.x == 0) {
    sti_agent(&arr[wg * 16], e);
    if (wg == 0) {
      int tries = 0;
      for (;;) {
        int mn = 0x7fffffff;
        #pragma unroll
        for (int i = 0; i < 32; ++i) { int v = ldi_agent(&arr[i * 16]); mn = (v < mn) ? v : mn; }
        if (mn >= e || ++tries >= (1 << 15)) break;   // watchdog: degrade diagnosably
        __builtin_amdgcn_s_sleep(1);
      }
      sti_agent(bfl, e);                              // release even on watchdog (no cascade)
    } else {
      int tries = 0;
      while (ldi_agent(bfl) < e) {
        if (++tries >= (1 << 15)) break;
        __builtin_amdgcn_s_sleep(1);
      }
    }
  }
  __syncthreads();
}

// SLOW fallback: device-scope threadfence protocol — round-2 proven.
__device__ __forceinline__ void slow_bar(int* ctr, int target) {
  __syncthreads();
  if (threadIdx.x == 0) {
    __threadfence();
    atomicAdd(ctr, 1);
    int tries = 0;
    while (__hip_atomic_load(ctr, __ATOMIC_RELAXED, __HIP_MEMORY_SCOPE_AGENT) < target) {
      __builtin_amdgcn_s_sleep(2);
      if (++tries >= (1 << 18)) break;
    }
    __threadfence();
  }
  __syncthreads();
}

// ---------------- main persistent scan kernel ----------------
__global__ void __launch_bounds__(256, 1) ebl_main(
    const float* __restrict__ x,   const float* __restrict__ bi,
    const float* __restrict__ bbb, const float* __restrict__ f1b, const float* __restrict__ f2b,
    const float* __restrict__ tab, const float* __restrict__ tbb,
    const float* __restrict__ predW, const float* __restrict__ predb,
    const float* __restrict__ enW,   const float* __restrict__ enb,
    float* __restrict__ out, char* __restrict__ ws)
{
  extern __shared__ char lds[];
  __shared__ float lbuf[4][16][36];       // [gate/matrix][col][row(padded)] f32
  __shared__ int   pflag;

  unsigned short* hsh = (unsigned short*)(ws + WS_H);
  unsigned short* hls = (unsigned short*)(ws + WS_HL);
  const unsigned short* wh  = (const unsigned short*)(ws + WS_WH);
  const unsigned short* bbw = (const unsigned short*)(ws + WS_BB);
  const unsigned short* ffw = (const unsigned short*)(ws + WS_FF);

  const int tid  = threadIdx.x;
  const int lane = tid & 63;
  const int wv   = tid >> 6;              // wave 0..3
  const int cl   = blockIdx.x & 7;        // cluster
  const int wg   = blockIdx.x >> 3;       // 0..31 within cluster
  const int rbase = cl * WPC;             // batch-row base of cluster
  const int jbase = wg * 16;              // hidden-column slice of this WG

  int* cctr = (int*)(ws + WS_BAR) + cl * 32;       // slow-path per-cluster counter
  int* dctr = (int*)(ws + WS_DC);                  // device startup barrier
  int* xccb = (int*)(ws + WS_XCC);
  int* pokb = (int*)(ws + WS_POK);
  int* pdat = (int*)(ws + WS_PDT);
  int* arr  = (int*)(ws + WS_ARR) + cl * (32 * 16); // flag-bar arrival slots (64B apart)
  int* bfl  = (int*)(ws + WS_BFL) + cl * 32;        // flag-bar broadcast flag (128B apart)

  const int l15 = lane & 15;
  const int l4  = lane >> 4;
  const int cc  = tid & 15;               // combine column
  const int rr  = tid >> 4;               // combine row

  // ---- one-time LDS weight residency ----
  for (int idx = tid; idx < 64 * 68; idx += 256) {
    int r = idx / 68, ch = idx - r * 68;
    int g = r >> 4, c = r & 15;
    bf16x8 v = *(const bf16x8*)(wh + (g * 512 + jbase + c) * KSn + ch * 8);
    *(bf16x8*)(lds + LB_WH + r * (KSP * 2) + ch * 16) = v;
  }
  for (int idx = tid; idx < 64 * 16; idx += 256) {
    int r = idx >> 4, ch = idx & 15;
    int m = r >> 4, c = r & 15;
    bf16x8 v = *(const bf16x8*)(ffw + m * (Hn * BBn) + (jbase + c) * BBn + ch * 8);
    *(bf16x8*)(lds + LB_FF + r * (BBP * 2) + ch * 16) = v;
  }

  // ---- stationary per-thread preloads ----
  float hp0[8], hp1[8], hpe[8];
  if (wv == 0) {
    #pragma unroll
    for (int j = 0; j < 8; ++j) {
      hp0[j] = predW[lane * 8 + j];
      hp1[j] = predW[512 + lane * 8 + j];
      hpe[j] = enW[lane * 8 + j];
    }
  }
  float biC[4];
  #pragma unroll
  for (int g = 0; g < 4; ++g) biC[g] = bi[g * 512 + jbase + cc];
  const float fb1 = f1b[jbase + cc], fb2v = f2b[jbase + cc];
  const float fta = tab[jbase + cc], ftb = tbb[jbase + cc];
  float bbBv[2] = { bbb[wv * 32 + l15], bbb[wv * 32 + 16 + l15] };

  float cst0 = 0.f, cst1 = 0.f;

  // ---- startup: publish XCC id, x_0; device barrier; XCD-uniformity ----
  int xcc;
  asm volatile("s_getreg_b32 %0, hwreg(HW_REG_XCC_ID)" : "=s"(xcc));
  if (tid == 0) { xccb[blockIdx.x] = xcc; pflag = 1; }
  if (tid < Fn) {
    int b = rbase + wg;
    hsh[b * KSn + 512 + tid] = f2bf(x[(b * Tn + 0) * Fn + tid]);
  }
  slow_bar(dctr, NWG);

  int refx = xccb[cl];
  int vx   = xccb[cl + 8 * (tid & 31)];
  const bool fast = (__ballot(vx != refx) == 0ull);

  int ep = 0;       // flag-bar epoch (per cluster)
  int slowph = 0;   // slow-bar phase (per cluster)

  // ---- probe: data propagation through the FLAG barrier, two stale-L1 rounds ----
  if (fast) {
    if (tid == 0) pdat[blockIdx.x * 16] = 1000 + blockIdx.x;
    flag_bar(arr, bfl, wg, ++ep);
    { int g = cl + 8 * (tid & 31); if (ldi_agent(&pdat[g * 16]) != 1000 + g) pflag = 0; }
    __syncthreads();
    if (tid == 0) pdat[blockIdx.x * 16] = 777000 + blockIdx.x * 3;
    flag_bar(arr, bfl, wg, ++ep);
    { int g = cl + 8 * (tid & 31); if (ldi_agent(&pdat[g * 16]) != 777000 + g * 3) pflag = 0; }
    __syncthreads();
    if (tid == 0) pokb[blockIdx.x] = pflag;
    __syncthreads();
  }
  slow_bar(dctr, 2 * NWG);

  int pv = pokb[cl + 8 * (tid & 31)];
  const bool fastrun = fast && (__ballot(pv == 0) == 0ull);

  const char* hshB = (const char*)hsh + rbase * (KSn * 2);
  const char* hlsB = (const char*)hls + rbase * (KSn * 2);

  for (int t = 0; t < Tn; ++t) {
    // ---------- fused heads for step t-1 (wave 0) ----------
    if (wv == 0 && t > 0) {
      const int b = rbase + wg;
      u64 q0 = ldq_agent((const char*)hsh + b * (KSn * 2) + lane * 16);
      u64 q1 = ldq_agent((const char*)hsh + b * (KSn * 2) + lane * 16 + 8);
      float s0 = 0.f, s1 = 0.f, se = 0.f;
      #pragma unroll
      for (int j = 0; j < 8; ++j) {
        unsigned short us = (unsigned short)(((j < 4) ? q0 : q1) >> (16 * (j & 3)));
        float hv = bf2f(us);
        s0 += hv * hp0[j]; s1 += hv * hp1[j]; se += hv * hpe[j];
      }
      #pragma unroll
      for (int off = 32; off > 0; off >>= 1) {
        s0 += __shfl_down(s0, off);
        s1 += __shfl_down(s1, off);
        se += __shfl_down(se, off);
      }
      if (lane == 0) {
        out[YO + b * (Tn * 2) + (t - 1) * 2 + 0] = s0 + predb[0];
        out[YO + b * (Tn * 2) + (t - 1) * 2 + 1] = s1 + predb[1];
        out[EO + b * Tn + (t - 1)]               = se + enb[0];
      }
    }
    // x_t into hlstm ext cols (consumed after bar0)
    if (tid < Fn) {
      int b = rbase + wg;
      hls[b * KSn + 512 + tid] = f2bf(x[(b * Tn + t) * Fn + tid]);
    }

    // ---------- stage A: h -> LDS; z = [h,x_t] @ Wh^T; gates; h_lstm ----------
    stage32(hshB, lds + LB_A, tid);
    __syncthreads();
    {
      f32x4 acc0 = {0.f, 0.f, 0.f, 0.f}, acc1 = {0.f, 0.f, 0.f, 0.f};
      const char* a0b = lds + LB_A + l15 * (KSP * 2) + l4 * 16;
      const char* a1b = a0b + 16 * (KSP * 2);
      const char* wb  = lds + LB_WH + (wv * 16 + l15) * (KSP * 2) + l4 * 16;
      #pragma unroll
      for (int ks = 0; ks < 17; ++ks) {
        bf16x8 a0 = *(const bf16x8*)(a0b + ks * 64);
        bf16x8 a1 = *(const bf16x8*)(a1b + ks * 64);
        bf16x8 b8 = *(const bf16x8*)(wb + ks * 64);
        acc0 = __builtin_amdgcn_mfma_f32_16x16x32_bf16(a0, b8, acc0, 0, 0, 0);
        acc1 = __builtin_amdgcn_mfma_f32_16x16x32_bf16(a1, b8, acc1, 0, 0, 0);
      }
      *(f32x4*)(&lbuf[wv][l15][l4 * 4])      = acc0;
      *(f32x4*)(&lbuf[wv][l15][16 + l4 * 4]) = acc1;
    }
    __syncthreads();
    {
      float zi0 = lbuf[0][cc][rr]      + biC[0];
      float zg0 = lbuf[1][cc][rr]      + biC[1];
      float zf0 = lbuf[2][cc][rr]      + biC[2];
      float zo0 = lbuf[3][cc][rr]      + biC[3];
      float zi1 = lbuf[0][cc][rr + 16] + biC[0];
      float zg1 = lbuf[1][cc][rr + 16] + biC[1];
      float zf1 = lbuf[2][cc][rr + 16] + biC[2];
      float zo1 = lbuf[3][cc][rr + 16] + biC[3];
      float cn0 = cst0 * sigm(zf0 + 1.f) + tanhx(zi0) * sigm(zg0);
      float cn1 = cst1 * sigm(zf1 + 1.f) + tanhx(zi1) * sigm(zg1);
      float hl0 = tanhx(cn0) * sigm(zo0);
      float hl1 = tanhx(cn1) * sigm(zo1);
      cst0 = cn0; cst1 = cn1;
      const int b0 = rbase + rr, b1 = rbase + rr + 16;
      hls[b0 * KSn + jbase + cc] = f2bf(hl0);
      hls[b1 * KSn + jbase + cc] = f2bf(hl1);
      if (t == Tn - 1) {
        out[CO + b0 * Hn + jbase + cc] = cn0;
        out[CO + b1 * Hn + jbase + cc] = cn1;
      }
    }
    ++ep;
    if (fastrun) flag_bar(arr, bfl, wg, ep);
    else { ++slowph; slow_bar(cctr, slowph * WPC); }

    // ---------- fused stage BC: hls -> LDS; feat (full, per-WG); ff; h_new ----------
    stage32(hlsB, lds + LB_A, tid);
    __syncthreads();
    {
      // bb-MFMA: wave wv computes feat cols [wv*32, wv*32+32) for all 32 rows
      f32x4 aB00 = {0.f,0.f,0.f,0.f}, aB01 = {0.f,0.f,0.f,0.f};
      f32x4 aB10 = {0.f,0.f,0.f,0.f}, aB11 = {0.f,0.f,0.f,0.f};
      const char* a0b = lds + LB_A + l15 * (KSP * 2) + l4 * 16;
      const char* a1b = a0b + 16 * (KSP * 2);
      const char* b0r = (const char*)bbw + (wv * 32 + l15) * (KSn * 2) + l4 * 16;
      const char* b1r = b0r + 16 * (KSn * 2);
      #pragma unroll
      for (int ks = 0; ks < 17; ++ks) {
        bf16x8 a0 = *(const bf16x8*)(a0b + ks * 64);
        bf16x8 a1 = *(const bf16x8*)(a1b + ks * 64);
        bf16x8 b0 = *(const bf16x8*)(b0r + ks * 64);
        bf16x8 b1 = *(const bf16x8*)(b1r + ks * 64);
        aB00 = __builtin_amdgcn_mfma_f32_16x16x32_bf16(a0, b0, aB00, 0, 0, 0);
        aB01 = __builtin_amdgcn_mfma_f32_16x16x32_bf16(a0, b1, aB01, 0, 0, 0);
        aB10 = __builtin_amdgcn_mfma_f32_16x16x32_bf16(a1, b0, aB10, 0, 0, 0);
        aB11 = __builtin_amdgcn_mfma_f32_16x16x32_bf16(a1, b1, aB11, 0, 0, 0);
      }
      unsigned short* ft = (unsigned short*)(lds + LB_FT);
      #pragma unroll
      for (int j = 0; j < 4; ++j) {
        int r0 = l4 * 4 + j, r1 = 16 + l4 * 4 + j;
        int c0 = wv * 32 + l15, c1 = wv * 32 + 16 + l15;
        ft[r0 * BBP + c0] = f2bf(1.7159f * tanhx(0.666f * (aB00[j] + bbBv[0])));
        ft[r0 * BBP + c1] = f2bf(1.7159f * tanhx(0.666f * (aB01[j] + bbBv[1])));
        ft[r1 * BBP + c0] = f2bf(1.7159f * tanhx(0.666f * (aB10[j] + bbBv[0])));
        ft[r1 * BBP + c1] = f2bf(1.7159f * tanhx(0.666f * (aB11[j] + bbBv[1])));
      }
    }
    __syncthreads();
    {
      f32x4 ac0 = {0.f, 0.f, 0.f, 0.f}, ac1 = {0.f, 0.f, 0.f, 0.f};
      const char* f0 = lds + LB_FT + l15 * (BBP * 2) + l4 * 16;
      const char* f1 = f0 + 16 * (BBP * 2);
      const char* wb = lds + LB_FF + (wv * 16 + l15) * (BBP * 2) + l4 * 16;
      #pragma unroll
      for (int ks = 0; ks < 4; ++ks) {
        bf16x8 a0 = *(const bf16x8*)(f0 + ks * 64);
        bf16x8 a1 = *(const bf16x8*)(f1 + ks * 64);
        bf16x8 b8 = *(const bf16x8*)(wb + ks * 64);
        ac0 = __builtin_amdgcn_mfma_f32_16x16x32_bf16(a0, b8, ac0, 0, 0, 0);
        ac1 = __builtin_amdgcn_mfma_f32_16x16x32_bf16(a1, b8, ac1, 0, 0, 0);
      }
      *(f32x4*)(&lbuf[wv][l15][l4 * 4])      = ac0;
      *(f32x4*)(&lbuf[wv][l15][16 + l4 * 4]) = ac1;
    }
    __syncthreads();
    {
      float p10 = lbuf[0][cc][rr] + fb1,      p20 = lbuf[1][cc][rr] + fb2v;
      float pa0 = lbuf[2][cc][rr] + fta,      pb0 = lbuf[3][cc][rr] + ftb;
      float p11 = lbuf[0][cc][rr + 16] + fb1, p21 = lbuf[1][cc][rr + 16] + fb2v;
      float pa1 = lbuf[2][cc][rr + 16] + fta, pb1 = lbuf[3][cc][rr + 16] + ftb;
      float f10 = tanhx(p10), f20 = tanhx(p20), ti0 = sigm(pa0 + pb0);
      float f11 = tanhx(p11), f21 = tanhx(p21), ti1 = sigm(pa1 + pb1);
      float hn0 = f10 + ti0 * (f20 - f10);
      float hn1 = f11 + ti1 * (f21 - f11);
      const int b0 = rbase + rr, b1 = rbase + rr + 16;
      hsh[b0 * KSn + jbase + cc] = f2bf(hn0);
      hsh[b1 * KSn + jbase + cc] = f2bf(hn1);
      if (t == Tn - 1) {
        out[HO + b0 * Hn + jbase + cc] = hn0;
        out[HO + b1 * Hn + jbase + cc] = hn1;
      }
    }
    if (t + 1 < Tn && tid < Fn) {
      int b = rbase + wg;
      hsh[b * KSn + 512 + tid] = f2bf(x[(b * Tn + t + 1) * Fn + tid]);
    }
    ++ep;
    if (fastrun) flag_bar(arr, bfl, wg, ep);
    else { ++slowph; slow_bar(cctr, slowph * WPC); }
  }

  // ---------- epilogue heads for t = Tn-1 ----------
  if (wv == 0) {
    const int b = rbase + wg;
    u64 q0 = ldq_agent((const char*)hsh + b * (KSn * 2) + lane * 16);
    u64 q1 = ldq_agent((const char*)hsh + b * (KSn * 2) + lane * 16 + 8);
    float s0 = 0.f, s1 = 0.f, se = 0.f;
    #pragma unroll
    for (int j = 0; j < 8; ++j) {
      unsigned short us = (unsigned short)(((j < 4) ? q0 : q1) >> (16 * (j & 3)));
      float hv = bf2f(us);
      s0 += hv * hp0[j]; s1 += hv * hp1[j]; se += hv * hpe[j];
    }
    #pragma unroll
    for (int off = 32; off > 0; off >>= 1) {
      s0 += __shfl_down(s0, off);
      s1 += __shfl_down(s1, off);
      se += __shfl_down(se, off);
    }
    if (lane == 0) {
      out[YO + b * (Tn * 2) + (Tn - 1) * 2 + 0] = s0 + predb[0];
      out[YO + b * (Tn * 2) + (Tn - 1) * 2 + 1] = s1 + predb[1];
      out[EO + b * Tn + (Tn - 1)]               = se + enb[0];
    }
  }
}

extern "C" void kernel_launch(void* const* d_in, const int* in_sizes, int n_in,
                              void* d_out, int out_size, void* d_ws, size_t ws_size,
                              hipStream_t stream) {
  const float* x   = (const float*)d_in[0];
  const float* Wi  = (const float*)d_in[1];
  const float* bi  = (const float*)d_in[2];
  const float* Wh  = (const float*)d_in[3];
  const float* bbW = (const float*)d_in[4];
  const float* bbb = (const float*)d_in[5];
  const float* f1W = (const float*)d_in[6];
  const float* f1b = (const float*)d_in[7];
  const float* f2W = (const float*)d_in[8];
  const float* f2b = (const float*)d_in[9];
  const float* taW = (const float*)d_in[10];
  const float* tab = (const float*)d_in[11];
  const float* tbW = (const float*)d_in[12];
  const float* tbb = (const float*)d_in[13];
  const float* pW  = (const float*)d_in[14];
  const float* pb  = (const float*)d_in[15];
  const float* eW  = (const float*)d_in[16];
  const float* eb  = (const float*)d_in[17];
  float* out = (float*)d_out;
  char* ws = (char*)d_ws;

  static_assert(DYN_LDS == 132096, "LDS layout");
  (void)hipFuncSetAttribute((const void*)ebl_main,
                            hipFuncAttributeMaxDynamicSharedMemorySize, DYN_LDS);

  // zero barriers + flag arrays + verdict/probe tables + activation buffers
  hipMemsetAsync(ws, 0, WS_WH, stream);
  prep_weights<<<2048, 256, 0, stream>>>(Wh, Wi, bbW, f1W, f2W, taW, tbW, ws);

  void* args[] = { (void*)&x, (void*)&bi, (void*)&bbb, (void*)&f1b, (void*)&f2b,
                   (void*)&tab, (void*)&tbb, (void*)&pW, (void*)&pb, (void*)&eW,
                   (void*)&eb, (void*)&out, (void*)&ws };
  hipLaunchCooperativeKernel((const void*)ebl_main, dim3(NWG), dim3(256), args,
                             DYN_LDS, stream);
}

// Round 11
// 9780.914 us; speedup vs baseline: 1.8133x; 1.8133x over previous
//
#include <hip/hip_runtime.h>

// ---- problem dims ----
#define Bn   256
#define Tn   512
#define Fn   5
#define Hn   512
#define BBn  128
#define KSn  544          // 512 (H) + 5 (x) + pad to 17*32
#define KSP  552          // LDS row stride (shorts) for 544-col tiles: +8 -> 2-way banks only
#define BBP  136          // LDS row stride (shorts) for 128-col tiles
#define NC   8            // clusters (XCD round-robin by blockIdx%8 — probed, not assumed)
#define WPC  32           // workgroups per cluster
#define NWG  (NC*WPC)

typedef __attribute__((ext_vector_type(8))) short bf16x8;
typedef __attribute__((ext_vector_type(4))) float f32x4;
typedef unsigned long long u64;

// ---- d_ws layout (bytes) ----
#define WS_BAR   0                        // per-cluster slow-path counters, 128B apart
#define WS_DC    2048                     // device-wide startup barrier counter
#define WS_XCC   4096                     // per-WG XCC id table (256 ints)
#define WS_POK   5120                     // per-WG probe verdicts
#define WS_PDT   6144                     // per-WG probe data slots (256 x 64B)
#define WS_H     24576                    // h_shared [Bn][KSn] bf16 (cols 512..516 = x_t, rest 0)
#define WS_HL    (WS_H   + Bn*KSn*2)      // hlstm    [Bn][KSn] bf16
#define WS_FEAT  (WS_HL  + Bn*KSn*2)      // 64KB region, reused for flag-barrier arrays:
#define WS_ARR   WS_FEAT                  //   arrival slots [8 clusters][32 WGs x 64B]
#define WS_WH    (WS_FEAT + Bn*BBn*2)     // Wh_ext   [2048][KSn] bf16 (k>=512 -> Wi, pad 0)
#define WS_BB    (WS_WH  + 2048*KSn*2)    // bb_ext   [128][KSn] bf16
#define WS_FF    (WS_BB  + 128*KSn*2)     // ff       [4][Hn][BBn] bf16

// ---- dynamic LDS layout (bytes) ----
#define LB_A     0                        // activation stage: 32*KSP*2 = 35328 (h / hlstm)
#define LB_WH    (LB_A + 32*KSP*2)        // Wh slice: [4 gates][16 cols][KSP] = 70656
#define LB_FF    (LB_WH + 64*KSP*2)       // ff slice: [4 mats][16 cols][BBP] = 17408
#define LB_FT    (LB_FF + 64*BBP*2)       // feat tile [32][BBP] bf16 = 8704
#define DYN_LDS  (LB_FT + 32*BBP*2)       // = 132096 (+9216 static lbuf = 141312 <= 160K)

// ---- d_out layout (floats) ----
#define YO 0
#define EO (Bn*Tn*2)
#define HO (EO + Bn*Tn)
#define CO (HO + Bn*Hn)

__device__ __forceinline__ unsigned short f2bf(float f) {
  union { float f; unsigned u; } v; v.f = f;
  unsigned r = v.u + 0x7FFFu + ((v.u >> 16) & 1u);
  return (unsigned short)(r >> 16);
}
__device__ __forceinline__ float bf2f(unsigned short u) {
  union { unsigned u; float f; } v; v.u = ((unsigned)u) << 16;
  return v.f;
}
__device__ __forceinline__ float sigm(float x) { return 1.f / (1.f + __expf(-x)); }
__device__ __forceinline__ float tanhx(float x) {
  float e = __expf(2.f * x);
  return 1.f - 2.f / (e + 1.f);
}

// PROVEN coherence primitives (rounds 7-10): relaxed agent-scope atomics (L1-bypassing,
// XCD-L2-served). Round-9's asm dwordx4-sc1 was stale -> permanently rejected.
__device__ __forceinline__ u64 ldq_agent(const void* p) {
  return __hip_atomic_load((const u64*)p, __ATOMIC_RELAXED, __HIP_MEMORY_SCOPE_AGENT);
}
__device__ __forceinline__ int ldi_agent(const void* p) {
  return __hip_atomic_load((const int*)p, __ATOMIC_RELAXED, __HIP_MEMORY_SCOPE_AGENT);
}
__device__ __forceinline__ void sti_agent(int* p, int v) {
  __hip_atomic_store(p, v, __ATOMIC_RELAXED, __HIP_MEMORY_SCOPE_AGENT);
}

// Stage a 32-row x 544-col bf16 tile from global into LDS (row stride KSP*2).
// 17 independent 8B agent loads -> statically-indexed regs, then LDS writes. Proven r8.
__device__ __forceinline__ void stage32(const char* src, char* dst, int tid) {
  u64 rg[17];
  #pragma unroll
  for (int i = 0; i < 17; ++i) rg[i] = ldq_agent(src + (tid + i * 256) * 8);
  #pragma unroll
  for (int i = 0; i < 17; ++i) {
    int idx = tid + i * 256;
    int r = idx / 136, ch = idx - r * 136;
    *(u64*)(dst + r * (KSP * 2) + ch * 8) = rg[i];
  }
}

// ---------------- weight prep ----------------
__global__ void __launch_bounds__(256) prep_weights(
    const float* __restrict__ Wh, const float* __restrict__ Wi, const float* __restrict__ bbW,
    const float* __restrict__ f1W, const float* __restrict__ f2W,
    const float* __restrict__ taW, const float* __restrict__ tbW, char* __restrict__ ws)
{
  unsigned short* wh = (unsigned short*)(ws + WS_WH);
  unsigned short* bb = (unsigned short*)(ws + WS_BB);
  unsigned short* ff = (unsigned short*)(ws + WS_FF);
  const int n1 = 2048 * KSn, n2 = 128 * KSn, n3 = Hn * BBn;
  const int ntot = n1 + n2 + 4 * n3;
  for (int i = blockIdx.x * blockDim.x + threadIdx.x; i < ntot; i += gridDim.x * blockDim.x) {
    if (i < n1) {
      int c = i / KSn, k = i % KSn;
      float v = (k < 512) ? Wh[c * 512 + k] : ((k < 517) ? Wi[c * 5 + (k - 512)] : 0.f);
      wh[i] = f2bf(v);
    } else if (i < n1 + n2) {
      int j = i - n1; int o = j / KSn, k = j % KSn;
      float v = (k < 512) ? bbW[o * 517 + 5 + k] : ((k < 517) ? bbW[o * 517 + (k - 512)] : 0.f);
      bb[j] = f2bf(v);
    } else {
      int j = i - n1 - n2; int m = j / n3; int r = j % n3;
      const float* src = (m == 0) ? f1W : (m == 1) ? f2W : (m == 2) ? taW : tbW;
      ff[j] = f2bf(src[r]);
    }
  }
}

// ---------------- barriers ----------------
// FLAG barrier v2. Round-10 lesson: a SINGLE thread polling 32 slots via atomic loads is
// a serialized latency chain (LLVM doesn't batch atomics: load->vmcnt(0) each, ~6.5us per
// poll round -> ~15us/barrier). v2: arrival = one agent store per WG (parallel, no RMW);
// detection = EVERY WG's wave 0 polls lane-per-slot (32-lane gather = ONE L2 latency per
// round) + __all ballot. No leader, no broadcast hop. Same proven memory primitives.
__device__ __forceinline__ void flag_bar(int* arr, int wg, int e, int tid) {
  __syncthreads();
  if (tid == 0) sti_agent(&arr[wg * 16], e);
  if (tid < 64) {
    int tries = 0;
    for (;;) {
      int v = (tid < 32) ? ldi_agent(&arr[tid * 16]) : e;
      if (__all(v >= e)) break;
      if (++tries >= (1 << 15)) break;   // watchdog: degrade diagnosably, never hang
      __builtin_amdgcn_s_sleep(1);
    }
  }
  __syncthreads();
}

// SLOW fallback: device-scope threadfence protocol — round-2 proven.
__device__ __forceinline__ void slow_bar(int* ctr, int target) {
  __syncthreads();
  if (threadIdx.x == 0) {
    __threadfence();
    atomicAdd(ctr, 1);
    int tries = 0;
    while (__hip_atomic_load(ctr, __ATOMIC_RELAXED, __HIP_MEMORY_SCOPE_AGENT) < target) {
      __builtin_amdgcn_s_sleep(2);
      if (++tries >= (1 << 18)) break;
    }
    __threadfence();
  }
  __syncthreads();
}

// ---------------- main persistent scan kernel ----------------
__global__ void __launch_bounds__(256, 1) ebl_main(
    const float* __restrict__ x,   const float* __restrict__ bi,
    const float* __restrict__ bbb, const float* __restrict__ f1b, const float* __restrict__ f2b,
    const float* __restrict__ tab, const float* __restrict__ tbb,
    const float* __restrict__ predW, const float* __restrict__ predb,
    const float* __restrict__ enW,   const float* __restrict__ enb,
    float* __restrict__ out, char* __restrict__ ws)
{
  extern __shared__ char lds[];
  __shared__ float lbuf[4][16][36];       // [gate/matrix][col][row(padded)] f32
  __shared__ int   pflag;

  unsigned short* hsh = (unsigned short*)(ws + WS_H);
  unsigned short* hls = (unsigned short*)(ws + WS_HL);
  const unsigned short* wh  = (const unsigned short*)(ws + WS_WH);
  const unsigned short* bbw = (const unsigned short*)(ws + WS_BB);
  const unsigned short* ffw = (const unsigned short*)(ws + WS_FF);

  const int tid  = threadIdx.x;
  const int lane = tid & 63;
  const int wv   = tid >> 6;              // wave 0..3
  const int cl   = blockIdx.x & 7;        // cluster
  const int wg   = blockIdx.x >> 3;       // 0..31 within cluster
  const int rbase = cl * WPC;             // batch-row base of cluster
  const int jbase = wg * 16;              // hidden-column slice of this WG

  int* cctr = (int*)(ws + WS_BAR) + cl * 32;        // slow-path per-cluster counter
  int* dctr = (int*)(ws + WS_DC);                   // device startup barrier
  int* xccb = (int*)(ws + WS_XCC);
  int* pokb = (int*)(ws + WS_POK);
  int* pdat = (int*)(ws + WS_PDT);
  int* arr  = (int*)(ws + WS_ARR) + cl * (32 * 16); // flag-bar arrival slots (64B apart)

  const int l15 = lane & 15;
  const int l4  = lane >> 4;
  const int cc  = tid & 15;               // combine column
  const int rr  = tid >> 4;               // combine row

  // ---- one-time LDS weight residency ----
  for (int idx = tid; idx < 64 * 68; idx += 256) {
    int r = idx / 68, ch = idx - r * 68;
    int g = r >> 4, c = r & 15;
    bf16x8 v = *(const bf16x8*)(wh + (g * 512 + jbase + c) * KSn + ch * 8);
    *(bf16x8*)(lds + LB_WH + r * (KSP * 2) + ch * 16) = v;
  }
  for (int idx = tid; idx < 64 * 16; idx += 256) {
    int r = idx >> 4, ch = idx & 15;
    int m = r >> 4, c = r & 15;
    bf16x8 v = *(const bf16x8*)(ffw + m * (Hn * BBn) + (jbase + c) * BBn + ch * 8);
    *(bf16x8*)(lds + LB_FF + r * (BBP * 2) + ch * 16) = v;
  }

  // ---- stationary per-thread preloads ----
  float hp0[8], hp1[8], hpe[8];
  if (wv == 0) {
    #pragma unroll
    for (int j = 0; j < 8; ++j) {
      hp0[j] = predW[lane * 8 + j];
      hp1[j] = predW[512 + lane * 8 + j];
      hpe[j] = enW[lane * 8 + j];
    }
  }
  float biC[4];
  #pragma unroll
  for (int g = 0; g < 4; ++g) biC[g] = bi[g * 512 + jbase + cc];
  const float fb1 = f1b[jbase + cc], fb2v = f2b[jbase + cc];
  const float fta = tab[jbase + cc], ftb = tbb[jbase + cc];
  float bbBv[2] = { bbb[wv * 32 + l15], bbb[wv * 32 + 16 + l15] };

  float cst0 = 0.f, cst1 = 0.f;

  // ---- startup: publish XCC id, x_0; device barrier; XCD-uniformity ----
  int xcc;
  asm volatile("s_getreg_b32 %0, hwreg(HW_REG_XCC_ID)" : "=s"(xcc));
  if (tid == 0) { xccb[blockIdx.x] = xcc; pflag = 1; }
  if (tid < Fn) {
    int b = rbase + wg;
    hsh[b * KSn + 512 + tid] = f2bf(x[(b * Tn + 0) * Fn + tid]);
  }
  slow_bar(dctr, NWG);

  int refx = xccb[cl];
  int vx   = xccb[cl + 8 * (tid & 31)];
  const bool fast = (__ballot(vx != refx) == 0ull);

  int ep = 0;       // flag-bar epoch (per cluster)
  int slowph = 0;   // slow-bar phase (per cluster)

  // ---- probe: data propagation through the FLAG barrier, two stale-L1 rounds ----
  if (fast) {
    if (tid == 0) pdat[blockIdx.x * 16] = 1000 + blockIdx.x;
    flag_bar(arr, wg, ++ep, tid);
    { int g = cl + 8 * (tid & 31); if (ldi_agent(&pdat[g * 16]) != 1000 + g) pflag = 0; }
    __syncthreads();
    if (tid == 0) pdat[blockIdx.x * 16] = 777000 + blockIdx.x * 3;
    flag_bar(arr, wg, ++ep, tid);
    { int g = cl + 8 * (tid & 31); if (ldi_agent(&pdat[g * 16]) != 777000 + g * 3) pflag = 0; }
    __syncthreads();
    if (tid == 0) pokb[blockIdx.x] = pflag;
    __syncthreads();
  }
  slow_bar(dctr, 2 * NWG);

  int pv = pokb[cl + 8 * (tid & 31)];
  const bool fastrun = fast && (__ballot(pv == 0) == 0ull);

  const char* hshB = (const char*)hsh + rbase * (KSn * 2);
  const char* hlsB = (const char*)hls + rbase * (KSn * 2);

  for (int t = 0; t < Tn; ++t) {
    // ---------- fused heads for step t-1 (wave 0) ----------
    if (wv == 0 && t > 0) {
      const int b = rbase + wg;
      u64 q0 = ldq_agent((const char*)hsh + b * (KSn * 2) + lane * 16);
      u64 q1 = ldq_agent((const char*)hsh + b * (KSn * 2) + lane * 16 + 8);
      float s0 = 0.f, s1 = 0.f, se = 0.f;
      #pragma unroll
      for (int j = 0; j < 8; ++j) {
        unsigned short us = (unsigned short)(((j < 4) ? q0 : q1) >> (16 * (j & 3)));
        float hv = bf2f(us);
        s0 += hv * hp0[j]; s1 += hv * hp1[j]; se += hv * hpe[j];
      }
      #pragma unroll
      for (int off = 32; off > 0; off >>= 1) {
        s0 += __shfl_down(s0, off);
        s1 += __shfl_down(s1, off);
        se += __shfl_down(se, off);
      }
      if (lane == 0) {
        out[YO + b * (Tn * 2) + (t - 1) * 2 + 0] = s0 + predb[0];
        out[YO + b * (Tn * 2) + (t - 1) * 2 + 1] = s1 + predb[1];
        out[EO + b * Tn + (t - 1)]               = se + enb[0];
      }
    }
    // x_t into hlstm ext cols (consumed after bar0)
    if (tid < Fn) {
      int b = rbase + wg;
      hls[b * KSn + 512 + tid] = f2bf(x[(b * Tn + t) * Fn + tid]);
    }

    // ---------- stage A: h -> LDS; z = [h,x_t] @ Wh^T; gates; h_lstm ----------
    stage32(hshB, lds + LB_A, tid);
    __syncthreads();
    {
      f32x4 acc0 = {0.f, 0.f, 0.f, 0.f}, acc1 = {0.f, 0.f, 0.f, 0.f};
      const char* a0b = lds + LB_A + l15 * (KSP * 2) + l4 * 16;
      const char* a1b = a0b + 16 * (KSP * 2);
      const char* wb  = lds + LB_WH + (wv * 16 + l15) * (KSP * 2) + l4 * 16;
      #pragma unroll
      for (int ks = 0; ks < 17; ++ks) {
        bf16x8 a0 = *(const bf16x8*)(a0b + ks * 64);
        bf16x8 a1 = *(const bf16x8*)(a1b + ks * 64);
        bf16x8 b8 = *(const bf16x8*)(wb + ks * 64);
        acc0 = __builtin_amdgcn_mfma_f32_16x16x32_bf16(a0, b8, acc0, 0, 0, 0);
        acc1 = __builtin_amdgcn_mfma_f32_16x16x32_bf16(a1, b8, acc1, 0, 0, 0);
      }
      *(f32x4*)(&lbuf[wv][l15][l4 * 4])      = acc0;
      *(f32x4*)(&lbuf[wv][l15][16 + l4 * 4]) = acc1;
    }
    __syncthreads();
    {
      float zi0 = lbuf[0][cc][rr]      + biC[0];
      float zg0 = lbuf[1][cc][rr]      + biC[1];
      float zf0 = lbuf[2][cc][rr]      + biC[2];
      float zo0 = lbuf[3][cc][rr]      + biC[3];
      float zi1 = lbuf[0][cc][rr + 16] + biC[0];
      float zg1 = lbuf[1][cc][rr + 16] + biC[1];
      float zf1 = lbuf[2][cc][rr + 16] + biC[2];
      float zo1 = lbuf[3][cc][rr + 16] + biC[3];
      float cn0 = cst0 * sigm(zf0 + 1.f) + tanhx(zi0) * sigm(zg0);
      float cn1 = cst1 * sigm(zf1 + 1.f) + tanhx(zi1) * sigm(zg1);
      float hl0 = tanhx(cn0) * sigm(zo0);
      float hl1 = tanhx(cn1) * sigm(zo1);
      cst0 = cn0; cst1 = cn1;
      const int b0 = rbase + rr, b1 = rbase + rr + 16;
      hls[b0 * KSn + jbase + cc] = f2bf(hl0);
      hls[b1 * KSn + jbase + cc] = f2bf(hl1);
      if (t == Tn - 1) {
        out[CO + b0 * Hn + jbase + cc] = cn0;
        out[CO + b1 * Hn + jbase + cc] = cn1;
      }
    }
    ++ep;
    if (fastrun) flag_bar(arr, wg, ep, tid);
    else { ++slowph; slow_bar(cctr, slowph * WPC); }

    // ---------- fused stage BC: hls -> LDS; feat (full, per-WG); ff; h_new ----------
    stage32(hlsB, lds + LB_A, tid);
    __syncthreads();
    {
      // bb-MFMA: wave wv computes feat cols [wv*32, wv*32+32) for all 32 rows
      f32x4 aB00 = {0.f,0.f,0.f,0.f}, aB01 = {0.f,0.f,0.f,0.f};
      f32x4 aB10 = {0.f,0.f,0.f,0.f}, aB11 = {0.f,0.f,0.f,0.f};
      const char* a0b = lds + LB_A + l15 * (KSP * 2) + l4 * 16;
      const char* a1b = a0b + 16 * (KSP * 2);
      const char* b0r = (const char*)bbw + (wv * 32 + l15) * (KSn * 2) + l4 * 16;
      const char* b1r = b0r + 16 * (KSn * 2);
      #pragma unroll
      for (int ks = 0; ks < 17; ++ks) {
        bf16x8 a0 = *(const bf16x8*)(a0b + ks * 64);
        bf16x8 a1 = *(const bf16x8*)(a1b + ks * 64);
        bf16x8 b0 = *(const bf16x8*)(b0r + ks * 64);
        bf16x8 b1 = *(const bf16x8*)(b1r + ks * 64);
        aB00 = __builtin_amdgcn_mfma_f32_16x16x32_bf16(a0, b0, aB00, 0, 0, 0);
        aB01 = __builtin_amdgcn_mfma_f32_16x16x32_bf16(a0, b1, aB01, 0, 0, 0);
        aB10 = __builtin_amdgcn_mfma_f32_16x16x32_bf16(a1, b0, aB10, 0, 0, 0);
        aB11 = __builtin_amdgcn_mfma_f32_16x16x32_bf16(a1, b1, aB11, 0, 0, 0);
      }
      unsigned short* ft = (unsigned short*)(lds + LB_FT);
      #pragma unroll
      for (int j = 0; j < 4; ++j) {
        int r0 = l4 * 4 + j, r1 = 16 + l4 * 4 + j;
        int c0 = wv * 32 + l15, c1 = wv * 32 + 16 + l15;
        ft[r0 * BBP + c0] = f2bf(1.7159f * tanhx(0.666f * (aB00[j] + bbBv[0])));
        ft[r0 * BBP + c1] = f2bf(1.7159f * tanhx(0.666f * (aB01[j] + bbBv[1])));
        ft[r1 * BBP + c0] = f2bf(1.7159f * tanhx(0.666f * (aB10[j] + bbBv[0])));
        ft[r1 * BBP + c1] = f2bf(1.7159f * tanhx(0.666f * (aB11[j] + bbBv[1])));
      }
    }
    __syncthreads();
    {
      f32x4 ac0 = {0.f, 0.f, 0.f, 0.f}, ac1 = {0.f, 0.f, 0.f, 0.f};
      const char* f0 = lds + LB_FT + l15 * (BBP * 2) + l4 * 16;
      const char* f1 = f0 + 16 * (BBP * 2);
      const char* wb = lds + LB_FF + (wv * 16 + l15) * (BBP * 2) + l4 * 16;
      #pragma unroll
      for (int ks = 0; ks < 4; ++ks) {
        bf16x8 a0 = *(const bf16x8*)(f0 + ks * 64);
        bf16x8 a1 = *(const bf16x8*)(f1 + ks * 64);
        bf16x8 b8 = *(const bf16x8*)(wb + ks * 64);
        ac0 = __builtin_amdgcn_mfma_f32_16x16x32_bf16(a0, b8, ac0, 0, 0, 0);
        ac1 = __builtin_amdgcn_mfma_f32_16x16x32_bf16(a1, b8, ac1, 0, 0, 0);
      }
      *(f32x4*)(&lbuf[wv][l15][l4 * 4])      = ac0;
      *(f32x4*)(&lbuf[wv][l15][16 + l4 * 4]) = ac1;
    }
    __syncthreads();
    {
      float p10 = lbuf[0][cc][rr] + fb1,      p20 = lbuf[1][cc][rr] + fb2v;
      float pa0 = lbuf[2][cc][rr] + fta,      pb0 = lbuf[3][cc][rr] + ftb;
      float p11 = lbuf[0][cc][rr + 16] + fb1, p21 = lbuf[1][cc][rr + 16] + fb2v;
      float pa1 = lbuf[2][cc][rr + 16] + fta, pb1 = lbuf[3][cc][rr + 16] + ftb;
      float f10 = tanhx(p10), f20 = tanhx(p20), ti0 = sigm(pa0 + pb0);
      float f11 = tanhx(p11), f21 = tanhx(p21), ti1 = sigm(pa1 + pb1);
      float hn0 = f10 + ti0 * (f20 - f10);
      float hn1 = f11 + ti1 * (f21 - f11);
      const int b0 = rbase + rr, b1 = rbase + rr + 16;
      hsh[b0 * KSn + jbase + cc] = f2bf(hn0);
      hsh[b1 * KSn + jbase + cc] = f2bf(hn1);
      if (t == Tn - 1) {
        out[HO + b0 * Hn + jbase + cc] = hn0;
        out[HO + b1 * Hn + jbase + cc] = hn1;
      }
    }
    if (t + 1 < Tn && tid < Fn) {
      int b = rbase + wg;
      hsh[b * KSn + 512 + tid] = f2bf(x[(b * Tn + t + 1) * Fn + tid]);
    }
    ++ep;
    if (fastrun) flag_bar(arr, wg, ep, tid);
    else { ++slowph; slow_bar(cctr, slowph * WPC); }
  }

  // ---------- epilogue heads for t = Tn-1 ----------
  if (wv == 0) {
    const int b = rbase + wg;
    u64 q0 = ldq_agent((const char*)hsh + b * (KSn * 2) + lane * 16);
    u64 q1 = ldq_agent((const char*)hsh + b * (KSn * 2) + lane * 16 + 8);
    float s0 = 0.f, s1 = 0.f, se = 0.f;
    #pragma unroll
    for (int j = 0; j < 8; ++j) {
      unsigned short us = (unsigned short)(((j < 4) ? q0 : q1) >> (16 * (j & 3)));
      float hv = bf2f(us);
      s0 += hv * hp0[j]; s1 += hv * hp1[j]; se += hv * hpe[j];
    }
    #pragma unroll
    for (int off = 32; off > 0; off >>= 1) {
      s0 += __shfl_down(s0, off);
      s1 += __shfl_down(s1, off);
      se += __shfl_down(se, off);
    }
    if (lane == 0) {
      out[YO + b * (Tn * 2) + (Tn - 1) * 2 + 0] = s0 + predb[0];
      out[YO + b * (Tn * 2) + (Tn - 1) * 2 + 1] = s1 + predb[1];
      out[EO + b * Tn + (Tn - 1)]               = se + enb[0];
    }
  }
}

extern "C" void kernel_launch(void* const* d_in, const int* in_sizes, int n_in,
                              void* d_out, int out_size, void* d_ws, size_t ws_size,
                              hipStream_t stream) {
  const float* x   = (const float*)d_in[0];
  const float* Wi  = (const float*)d_in[1];
  const float* bi  = (const float*)d_in[2];
  const float* Wh  = (const float*)d_in[3];
  const float* bbW = (const float*)d_in[4];
  const float* bbb = (const float*)d_in[5];
  const float* f1W = (const float*)d_in[6];
  const float* f1b = (const float*)d_in[7];
  const float* f2W = (const float*)d_in[8];
  const float* f2b = (const float*)d_in[9];
  const float* taW = (const float*)d_in[10];
  const float* tab = (const float*)d_in[11];
  const float* tbW = (const float*)d_in[12];
  const float* tbb = (const float*)d_in[13];
  const float* pW  = (const float*)d_in[14];
  const float* pb  = (const float*)d_in[15];
  const float* eW  = (const float*)d_in[16];
  const float* eb  = (const float*)d_in[17];
  float* out = (float*)d_out;
  char* ws = (char*)d_ws;

  static_assert(DYN_LDS == 132096, "LDS layout");
  (void)hipFuncSetAttribute((const void*)ebl_main,
                            hipFuncAttributeMaxDynamicSharedMemorySize, DYN_LDS);

  // zero barriers + flag arrays + verdict/probe tables + activation buffers
  hipMemsetAsync(ws, 0, WS_WH, stream);
  prep_weights<<<2048, 256, 0, stream>>>(Wh, Wi, bbW, f1W, f2W, taW, tbW, ws);

  void* args[] = { (void*)&x, (void*)&bi, (void*)&bbb, (void*)&f1b, (void*)&f2b,
                   (void*)&tab, (void*)&tbb, (void*)&pW, (void*)&pb, (void*)&eW,
                   (void*)&eb, (void*)&out, (void*)&ws };
  hipLaunchCooperativeKernel((const void*)ebl_main, dim3(NWG), dim3(256), args,
                             DYN_LDS, stream);
}